// Round 3
// baseline (296.362 us; speedup 1.0000x reference)
//
#include <hip/hip_runtime.h>
#include <math.h>
#include <float.h>

#define B_SZ 512
#define C_SZ 1000
#define D_SZ 512
#define K_TOP 10
#define K2 1024                       // 2*D: [x^2 | x] vs [rd | -2*rd*p]
#define NSPLIT 8
#define KSPLIT (K2 / NSPLIT)          // 128
#define BC (B_SZ * C_SZ)

// ws layout (floats)
#define W_OFF   0                     // C x K2 = 1024000
#define T3_OFF  (W_OFF + C_SZ * K2)   // 1024 (padded)
#define PART_OFF (T3_OFF + 1024)      // NSPLIT x B x C = 4096000
// total ~5.1M floats ~20.5 MB (ws is 256 MiB)

// ---------------------------------------------------------------------------
// Prep: one wave per class row (4 classes/block, 250 blocks).
// rd = softmax(min-trick); W[c,0:512]=rd, W[c,512:1024]=-2*rd*p,
// t3[c] = sum rd*p^2.  Pure shuffle reductions, no __syncthreads.
// ---------------------------------------------------------------------------
__global__ __launch_bounds__(256) void prep_kernel(const float* __restrict__ protos,
                                                   const float* __restrict__ ex2,
                                                   const float* __restrict__ ex1,
                                                   const int* __restrict__ cls_num,
                                                   float* __restrict__ ws) {
    float* W  = ws + W_OFF;
    float* t3 = ws + T3_OFF;
    const int wid  = threadIdx.x >> 6;
    const int lane = threadIdx.x & 63;
    const int c = blockIdx.x * 4 + wid;

    const size_t rb = (size_t)c * D_SZ + lane * 8;
    float e2v[8], e1v[8], pv[8];
    *(float4*)&e2v[0] = *(const float4*)(ex2 + rb);
    *(float4*)&e2v[4] = *(const float4*)(ex2 + rb + 4);
    *(float4*)&e1v[0] = *(const float4*)(ex1 + rb);
    *(float4*)&e1v[4] = *(const float4*)(ex1 + rb + 4);
    *(float4*)&pv[0]  = *(const float4*)(protos + rb);
    *(float4*)&pv[4]  = *(const float4*)(protos + rb + 4);
    const float N = (float)cls_num[c];

    float v[8], mn = FLT_MAX;
    #pragma unroll
    for (int k = 0; k < 8; k++) {
        v[k] = sqrtf(N * e2v[k] * e2v[k] - e1v[k] * e1v[k]);
        mn = fminf(mn, v[k]);
    }
    #pragma unroll
    for (int off = 1; off < 64; off <<= 1) mn = fminf(mn, __shfl_xor(mn, off));

    float ev[8], s = 0.f;
    #pragma unroll
    for (int k = 0; k < 8; k++) { ev[k] = expf(mn - v[k]); s += ev[k]; }
    #pragma unroll
    for (int off = 1; off < 64; off <<= 1) s += __shfl_xor(s, off);
    const float inv = 1.0f / s;

    float w1[8], w2[8], t = 0.f;
    #pragma unroll
    for (int k = 0; k < 8; k++) {
        const float rdv = ev[k] * inv;
        w1[k] = rdv;
        w2[k] = -2.0f * rdv * pv[k];
        t = fmaf(rdv * pv[k], pv[k], t);
    }
    float* wr = W + (size_t)c * K2 + lane * 8;
    *(float4*)(wr)            = *(float4*)&w1[0];
    *(float4*)(wr + 4)        = *(float4*)&w1[4];
    *(float4*)(wr + D_SZ)     = *(float4*)&w2[0];
    *(float4*)(wr + D_SZ + 4) = *(float4*)&w2[4];
    #pragma unroll
    for (int off = 1; off < 64; off <<= 1) t += __shfl_xor(t, off);
    if (lane == 0) t3[c] = t;
}

// ---------------------------------------------------------------------------
// GEMM: part[z][b][c] = sum_{k in z-chunk} A[b,k]*W[c,k]
// A is virtual: A[b,k] = x[b,k]^2 (k<512) else x[b,k-512]; computed in staging.
// 64x64 tile, KB=32, 256 threads, 4x4 micro, splitK=8.
// Grid 16 x 8 x 8 = 1024 blocks -> 4 blocks/CU, 16 waves/CU.
// Register prefetch of next chunk overlaps global latency with FMAs.
// ---------------------------------------------------------------------------
#define TM 64
#define TN 64
#define KB 32

__global__ __launch_bounds__(256) void gemm_kernel(const float* __restrict__ x,
                                                   const float* __restrict__ Wm,
                                                   float* __restrict__ part) {
    __shared__ float as[KB][TM + 4];   // stride 68: float4-aligned cols
    __shared__ float wsm[KB][TN + 4];

    const int tid = threadIdx.x;
    const int tx = tid & 15;           // c direction (x4)
    const int ty = tid >> 4;           // b direction (x4)
    const int c0 = blockIdx.x * TN;
    const int b0 = blockIdx.y * TM;
    const int kz = blockIdx.z;

    // staging coords: two float4 loads per thread (A-tile and W-tile)
    const int row0 = tid >> 3;              // 0..31
    const int row1 = row0 + 32;             // 32..63
    const int col4 = (tid & 7) * 4;         // 0,4,...,28

    const bool sq = (kz < NSPLIT / 2);      // first half of K2 -> x^2
    const int khalf = sq ? kz * KSPLIT : kz * KSPLIT - D_SZ;

    float acc[4][4] = {};
    float4 pa0, pa1, pw0, pw1;

    // prefetch chunk 0
    {
        const int k0 = khalf;
        pa0 = *(const float4*)(x + (size_t)(b0 + row0) * D_SZ + k0 + col4);
        pa1 = *(const float4*)(x + (size_t)(b0 + row1) * D_SZ + k0 + col4);
        const int kw = kz * KSPLIT;
        const int cc0 = c0 + row0, cc1 = c0 + row1;
        pw0 = (cc0 < C_SZ) ? *(const float4*)(Wm + (size_t)cc0 * K2 + kw + col4)
                           : make_float4(0.f, 0.f, 0.f, 0.f);
        pw1 = (cc1 < C_SZ) ? *(const float4*)(Wm + (size_t)cc1 * K2 + kw + col4)
                           : make_float4(0.f, 0.f, 0.f, 0.f);
    }

    #pragma unroll
    for (int ch = 0; ch < KSPLIT / KB; ch++) {
        float4 a0 = pa0, a1 = pa1;
        if (sq) {
            a0.x *= a0.x; a0.y *= a0.y; a0.z *= a0.z; a0.w *= a0.w;
            a1.x *= a1.x; a1.y *= a1.y; a1.z *= a1.z; a1.w *= a1.w;
        }
        as[col4 + 0][row0] = a0.x; as[col4 + 1][row0] = a0.y;
        as[col4 + 2][row0] = a0.z; as[col4 + 3][row0] = a0.w;
        as[col4 + 0][row1] = a1.x; as[col4 + 1][row1] = a1.y;
        as[col4 + 2][row1] = a1.z; as[col4 + 3][row1] = a1.w;
        wsm[col4 + 0][row0] = pw0.x; wsm[col4 + 1][row0] = pw0.y;
        wsm[col4 + 2][row0] = pw0.z; wsm[col4 + 3][row0] = pw0.w;
        wsm[col4 + 0][row1] = pw1.x; wsm[col4 + 1][row1] = pw1.y;
        wsm[col4 + 2][row1] = pw1.z; wsm[col4 + 3][row1] = pw1.w;
        __syncthreads();

        if (ch + 1 < KSPLIT / KB) {
            const int k0 = khalf + (ch + 1) * KB;
            pa0 = *(const float4*)(x + (size_t)(b0 + row0) * D_SZ + k0 + col4);
            pa1 = *(const float4*)(x + (size_t)(b0 + row1) * D_SZ + k0 + col4);
            const int kw = kz * KSPLIT + (ch + 1) * KB;
            const int cc0 = c0 + row0, cc1 = c0 + row1;
            if (cc0 < C_SZ) pw0 = *(const float4*)(Wm + (size_t)cc0 * K2 + kw + col4);
            if (cc1 < C_SZ) pw1 = *(const float4*)(Wm + (size_t)cc1 * K2 + kw + col4);
        }

        #pragma unroll
        for (int kk = 0; kk < KB; kk++) {
            const float4 av4 = *(const float4*)&as[kk][ty * 4];
            const float4 wv4 = *(const float4*)&wsm[kk][tx * 4];
            const float a[4] = {av4.x, av4.y, av4.z, av4.w};
            const float w[4] = {wv4.x, wv4.y, wv4.z, wv4.w};
            #pragma unroll
            for (int i = 0; i < 4; i++)
                #pragma unroll
                for (int j = 0; j < 4; j++)
                    acc[i][j] = fmaf(a[i], w[j], acc[i][j]);
        }
        __syncthreads();
    }

    float* o = part + (size_t)kz * BC;
    #pragma unroll
    for (int i = 0; i < 4; i++) {
        const int b = b0 + ty * 4 + i;
        const int c = c0 + tx * 4;
        if (c + 3 < C_SZ) {
            float4 v = {acc[i][0], acc[i][1], acc[i][2], acc[i][3]};
            *(float4*)(o + (size_t)b * C_SZ + c) = v;
        } else {
            #pragma unroll
            for (int j = 0; j < 4; j++)
                if (c + j < C_SZ) o[(size_t)b * C_SZ + c + j] = acc[i][j];
        }
    }
}

// ---------------------------------------------------------------------------
// Top-K: per row, sum the 8 split-K partials + t3, then 10x butterfly min
// with index tie-break (lower index wins == lax.top_k stability).
// out[0..B): predict (float-encoded int), out[B..): topk_conf [B][K]
// ---------------------------------------------------------------------------
__global__ __launch_bounds__(256) void topk_kernel(const float* __restrict__ ws,
                                                   const int* __restrict__ proto_label,
                                                   float* __restrict__ out) {
    const float* part = ws + PART_OFF;
    const float* t3   = ws + T3_OFF;
    const int wid = threadIdx.x >> 6;
    const int lane = threadIdx.x & 63;
    const int b = blockIdx.x * 4 + wid;

    float vals[16];
    #pragma unroll
    for (int j = 0; j < 16; j++) {
        const int c = lane + j * 64;
        if (c < C_SZ) {
            const size_t idx = (size_t)b * C_SZ + c;
            float s = t3[c];
            #pragma unroll
            for (int z = 0; z < NSPLIT; z++)
                s += part[(size_t)z * BC + idx];
            vals[j] = s;
        } else {
            vals[j] = FLT_MAX;
        }
    }

    float kv[K_TOP];
    int ki[K_TOP];
    for (int t = 0; t < K_TOP; t++) {
        float bv = FLT_MAX;
        int bi = 0x7fffffff;
        #pragma unroll
        for (int j = 0; j < 16; j++) {
            const int c = lane + j * 64;
            if (vals[j] < bv) { bv = vals[j]; bi = c; }
        }
        #pragma unroll
        for (int off = 1; off < 64; off <<= 1) {
            const float ov = __shfl_xor(bv, off);
            const int oi = __shfl_xor(bi, off);
            if (ov < bv || (ov == bv && oi < bi)) { bv = ov; bi = oi; }
        }
        kv[t] = bv;
        ki[t] = bi;
        if ((bi & 63) == lane) vals[bi >> 6] = FLT_MAX;
    }

    if (lane == 0) {
        float S = 0.f;
        #pragma unroll
        for (int t = 0; t < K_TOP; t++) S += kv[t];
        float conf[K_TOP];
        #pragma unroll
        for (int t = 0; t < K_TOP; t++) {
            conf[t] = S / kv[t];
            out[B_SZ + b * K_TOP + t] = conf[t];
        }
        int best = 0;
        for (int t = 1; t < K_TOP; t++)
            if (conf[t] > conf[best]) best = t;
        out[b] = (float)proto_label[ki[best]];
    }
}

extern "C" void kernel_launch(void* const* d_in, const int* in_sizes, int n_in,
                              void* d_out, int out_size, void* d_ws, size_t ws_size,
                              hipStream_t stream) {
    const float* x           = (const float*)d_in[0];
    const float* protos      = (const float*)d_in[1];
    const float* ex2         = (const float*)d_in[2];
    const float* ex1         = (const float*)d_in[3];
    const int*   cls_num     = (const int*)d_in[4];
    const int*   proto_label = (const int*)d_in[5];

    float* ws  = (float*)d_ws;
    float* out = (float*)d_out;

    prep_kernel<<<C_SZ / 4, 256, 0, stream>>>(protos, ex2, ex1, cls_num, ws);

    dim3 g2((C_SZ + TN - 1) / TN, B_SZ / TM, NSPLIT);   // 16 x 8 x 8 = 1024
    gemm_kernel<<<g2, 256, 0, stream>>>(x, ws + W_OFF, ws + PART_OFF);

    topk_kernel<<<B_SZ / 4, 256, 0, stream>>>(ws, proto_label, out);
}

// Round 4
// 108.015 us; speedup vs baseline: 2.7437x; 2.7437x over previous
//
#include <hip/hip_runtime.h>
#include <math.h>
#include <float.h>

#define B_SZ 512
#define C_SZ 1000
#define D_SZ 512
#define K_TOP 10
#define K2 1024                       // 2*D: [x^2 | x] vs [rd | -2*rd*p]
#define NSPLIT 8
#define KSPLIT (K2 / NSPLIT)          // 128
#define BC (B_SZ * C_SZ)

// ws layout (floats)
#define W_OFF   0                     // C x K2 = 1024000
#define T3_OFF  (W_OFF + C_SZ * K2)   // 1024 (padded)
#define PART_OFF (T3_OFF + 1024)      // NSPLIT x B x C = 4096000
// total ~5.1M floats ~20.5 MB (ws is larger; harness re-poisons whole ws)

// ---------------------------------------------------------------------------
// Prep: one wave per class row (4 classes/block, 250 blocks).
// rd = softmax(min-trick); W[c,0:512]=rd, W[c,512:1024]=-2*rd*p,
// t3[c] = sum rd*p^2.  Pure shuffle reductions, no __syncthreads.
// ---------------------------------------------------------------------------
__global__ __launch_bounds__(256) void prep_kernel(const float* __restrict__ protos,
                                                   const float* __restrict__ ex2,
                                                   const float* __restrict__ ex1,
                                                   const int* __restrict__ cls_num,
                                                   float* __restrict__ ws) {
    float* W  = ws + W_OFF;
    float* t3 = ws + T3_OFF;
    const int wid  = threadIdx.x >> 6;
    const int lane = threadIdx.x & 63;
    const int c = blockIdx.x * 4 + wid;

    const size_t rb = (size_t)c * D_SZ + lane * 8;
    float e2v[8], e1v[8], pv[8];
    *(float4*)&e2v[0] = *(const float4*)(ex2 + rb);
    *(float4*)&e2v[4] = *(const float4*)(ex2 + rb + 4);
    *(float4*)&e1v[0] = *(const float4*)(ex1 + rb);
    *(float4*)&e1v[4] = *(const float4*)(ex1 + rb + 4);
    *(float4*)&pv[0]  = *(const float4*)(protos + rb);
    *(float4*)&pv[4]  = *(const float4*)(protos + rb + 4);
    const float N = (float)cls_num[c];

    float v[8], mn = FLT_MAX;
    #pragma unroll
    for (int k = 0; k < 8; k++) {
        v[k] = sqrtf(N * e2v[k] * e2v[k] - e1v[k] * e1v[k]);
        mn = fminf(mn, v[k]);
    }
    #pragma unroll
    for (int off = 1; off < 64; off <<= 1) mn = fminf(mn, __shfl_xor(mn, off));

    float ev[8], s = 0.f;
    #pragma unroll
    for (int k = 0; k < 8; k++) { ev[k] = expf(mn - v[k]); s += ev[k]; }
    #pragma unroll
    for (int off = 1; off < 64; off <<= 1) s += __shfl_xor(s, off);
    const float inv = 1.0f / s;

    float w1[8], w2[8], t = 0.f;
    #pragma unroll
    for (int k = 0; k < 8; k++) {
        const float rdv = ev[k] * inv;
        w1[k] = rdv;
        w2[k] = -2.0f * rdv * pv[k];
        t = fmaf(rdv * pv[k], pv[k], t);
    }
    float* wr = W + (size_t)c * K2 + lane * 8;
    *(float4*)(wr)            = *(float4*)&w1[0];
    *(float4*)(wr + 4)        = *(float4*)&w1[4];
    *(float4*)(wr + D_SZ)     = *(float4*)&w2[0];
    *(float4*)(wr + D_SZ + 4) = *(float4*)&w2[4];
    #pragma unroll
    for (int off = 1; off < 64; off <<= 1) t += __shfl_xor(t, off);
    if (lane == 0) t3[c] = t;
}

// ---------------------------------------------------------------------------
// GEMM: part[z][b][c] = sum_{k in z-chunk} A[b,k]*W[c,k]
// A is virtual: A[b,k] = x[b,k]^2 (k<512) else x[b,k-512]; computed in staging.
// 64x64 tile, KB=32, 256 threads, 4x4 micro, splitK=8.
// Grid 16 x 8 x 8 = 1024 blocks -> 4 blocks/CU, 16 waves/CU.
// SIMPLE runtime K-loop, no register prefetch, no outer unroll:
// R3's unroll+prefetch variant hit VGPR=256 + scratch spill (430 MB writes).
// __launch_bounds__(256,4) caps the allocator at ~128 VGPR (R2 measured 52).
// ---------------------------------------------------------------------------
#define TM 64
#define TN 64
#define KB 32

__global__ __launch_bounds__(256, 4) void gemm_kernel(const float* __restrict__ x,
                                                      const float* __restrict__ Wm,
                                                      float* __restrict__ part) {
    __shared__ float as[KB][TM + 4];   // stride 68: float4-aligned cols
    __shared__ float wsm[KB][TN + 4];

    const int tid = threadIdx.x;
    const int tx = tid & 15;           // c direction (x4)
    const int ty = tid >> 4;           // b direction (x4)
    const int c0 = blockIdx.x * TN;
    const int b0 = blockIdx.y * TM;
    const int kz = blockIdx.z;

    // staging coords: two float4 loads per thread per matrix
    const int row0 = tid >> 3;              // 0..31
    const int row1 = row0 + 32;             // 32..63
    const int col4 = (tid & 7) * 4;         // 0,4,...,28

    const bool sq = (kz < NSPLIT / 2);      // first half of K2 -> x^2
    const int khalf0 = sq ? kz * KSPLIT : kz * KSPLIT - D_SZ;

    float acc[4][4] = {};

    for (int ch = 0; ch < KSPLIT / KB; ch++) {
        const int kx = khalf0 + ch * KB;         // offset into x row
        const int kw = kz * KSPLIT + ch * KB;    // offset into W row

        float4 a0 = *(const float4*)(x + (size_t)(b0 + row0) * D_SZ + kx + col4);
        float4 a1 = *(const float4*)(x + (size_t)(b0 + row1) * D_SZ + kx + col4);
        if (sq) {
            a0.x *= a0.x; a0.y *= a0.y; a0.z *= a0.z; a0.w *= a0.w;
            a1.x *= a1.x; a1.y *= a1.y; a1.z *= a1.z; a1.w *= a1.w;
        }
        const int cc0 = c0 + row0, cc1 = c0 + row1;
        float4 w0 = make_float4(0.f, 0.f, 0.f, 0.f);
        float4 w1 = make_float4(0.f, 0.f, 0.f, 0.f);
        if (cc0 < C_SZ) w0 = *(const float4*)(Wm + (size_t)cc0 * K2 + kw + col4);
        if (cc1 < C_SZ) w1 = *(const float4*)(Wm + (size_t)cc1 * K2 + kw + col4);

        as[col4 + 0][row0] = a0.x; as[col4 + 1][row0] = a0.y;
        as[col4 + 2][row0] = a0.z; as[col4 + 3][row0] = a0.w;
        as[col4 + 0][row1] = a1.x; as[col4 + 1][row1] = a1.y;
        as[col4 + 2][row1] = a1.z; as[col4 + 3][row1] = a1.w;
        wsm[col4 + 0][row0] = w0.x; wsm[col4 + 1][row0] = w0.y;
        wsm[col4 + 2][row0] = w0.z; wsm[col4 + 3][row0] = w0.w;
        wsm[col4 + 0][row1] = w1.x; wsm[col4 + 1][row1] = w1.y;
        wsm[col4 + 2][row1] = w1.z; wsm[col4 + 3][row1] = w1.w;
        __syncthreads();

        #pragma unroll
        for (int kk = 0; kk < KB; kk++) {
            const float4 av4 = *(const float4*)&as[kk][ty * 4];
            const float4 wv4 = *(const float4*)&wsm[kk][tx * 4];
            const float a[4] = {av4.x, av4.y, av4.z, av4.w};
            const float w[4] = {wv4.x, wv4.y, wv4.z, wv4.w};
            #pragma unroll
            for (int i = 0; i < 4; i++)
                #pragma unroll
                for (int j = 0; j < 4; j++)
                    acc[i][j] = fmaf(a[i], w[j], acc[i][j]);
        }
        __syncthreads();
    }

    float* o = part + (size_t)kz * BC;
    #pragma unroll
    for (int i = 0; i < 4; i++) {
        const int b = b0 + ty * 4 + i;
        const int c = c0 + tx * 4;
        if (c + 3 < C_SZ) {
            float4 v = {acc[i][0], acc[i][1], acc[i][2], acc[i][3]};
            *(float4*)(o + (size_t)b * C_SZ + c) = v;
        } else {
            #pragma unroll
            for (int j = 0; j < 4; j++)
                if (c + j < C_SZ) o[(size_t)b * C_SZ + c + j] = acc[i][j];
        }
    }
}

// ---------------------------------------------------------------------------
// Top-K: per row, sum the 8 split-K partials + t3, then 10x butterfly min
// with index tie-break (lower index wins == lax.top_k stability).
// out[0..B): predict (float-encoded int), out[B..): topk_conf [B][K]
// ---------------------------------------------------------------------------
__global__ __launch_bounds__(256) void topk_kernel(const float* __restrict__ ws,
                                                   const int* __restrict__ proto_label,
                                                   float* __restrict__ out) {
    const float* part = ws + PART_OFF;
    const float* t3   = ws + T3_OFF;
    const int wid = threadIdx.x >> 6;
    const int lane = threadIdx.x & 63;
    const int b = blockIdx.x * 4 + wid;

    float vals[16];
    #pragma unroll
    for (int j = 0; j < 16; j++) {
        const int c = lane + j * 64;
        if (c < C_SZ) {
            const size_t idx = (size_t)b * C_SZ + c;
            float s = t3[c];
            #pragma unroll
            for (int z = 0; z < NSPLIT; z++)
                s += part[(size_t)z * BC + idx];
            vals[j] = s;
        } else {
            vals[j] = FLT_MAX;
        }
    }

    float kv[K_TOP];
    int ki[K_TOP];
    for (int t = 0; t < K_TOP; t++) {
        float bv = FLT_MAX;
        int bi = 0x7fffffff;
        #pragma unroll
        for (int j = 0; j < 16; j++) {
            const int c = lane + j * 64;
            if (vals[j] < bv) { bv = vals[j]; bi = c; }
        }
        #pragma unroll
        for (int off = 1; off < 64; off <<= 1) {
            const float ov = __shfl_xor(bv, off);
            const int oi = __shfl_xor(bi, off);
            if (ov < bv || (ov == bv && oi < bi)) { bv = ov; bi = oi; }
        }
        kv[t] = bv;
        ki[t] = bi;
        if ((bi & 63) == lane) vals[bi >> 6] = FLT_MAX;
    }

    if (lane == 0) {
        float S = 0.f;
        #pragma unroll
        for (int t = 0; t < K_TOP; t++) S += kv[t];
        float conf[K_TOP];
        #pragma unroll
        for (int t = 0; t < K_TOP; t++) {
            conf[t] = S / kv[t];
            out[B_SZ + b * K_TOP + t] = conf[t];
        }
        int best = 0;
        for (int t = 1; t < K_TOP; t++)
            if (conf[t] > conf[best]) best = t;
        out[b] = (float)proto_label[ki[best]];
    }
}

extern "C" void kernel_launch(void* const* d_in, const int* in_sizes, int n_in,
                              void* d_out, int out_size, void* d_ws, size_t ws_size,
                              hipStream_t stream) {
    const float* x           = (const float*)d_in[0];
    const float* protos      = (const float*)d_in[1];
    const float* ex2         = (const float*)d_in[2];
    const float* ex1         = (const float*)d_in[3];
    const int*   cls_num     = (const int*)d_in[4];
    const int*   proto_label = (const int*)d_in[5];

    float* ws  = (float*)d_ws;
    float* out = (float*)d_out;

    prep_kernel<<<C_SZ / 4, 256, 0, stream>>>(protos, ex2, ex1, cls_num, ws);

    dim3 g2((C_SZ + TN - 1) / TN, B_SZ / TM, NSPLIT);   // 16 x 8 x 8 = 1024
    gemm_kernel<<<g2, 256, 0, stream>>>(x, ws + W_OFF, ws + PART_OFF);

    topk_kernel<<<B_SZ / 4, 256, 0, stream>>>(ws, proto_label, out);
}